// Round 6
// baseline (22268.344 us; speedup 1.0000x reference)
//
#include <hip/hip_runtime.h>
#include <hip/hip_bf16.h>
#include <math.h>

#define SLEN 4096
#define LCH 24
#define EMB 300
#define CHE 25
#define CHO 25
#define XIN 325      // EMB + CHO
#define HID 512
#define GDIM 2048    // 4*HID
#define NTAG 11
#define TAG_START 9
#define TAG_STOP 10
#define NEGV (-10000.0f)
#define NW 32        // workgroups for the fused BiLSTM (both directions)
#define SENT 0x7FC00000u   // NaN sentinel: h = sigm*tanh can never be NaN

// ---- ws layout (float units) ----
#define WT_F_O   0u
#define WT_B_O   (WT_F_O + XIN*GDIM)          // Wih^T forward/backward
#define CF_O     (WT_B_O + XIN*GDIM)          // char_feat [S][25]
#define GF_O     (CF_O + SLEN*CHO)            // G forward [S][2048]
#define GB_O     (GF_O + SLEN*GDIM)
#define HSF_O    (GB_O + SLEN*GDIM)           // hs forward [S][512]
#define HSB_O    (HSF_O + SLEN*HID)
#define FEATS_O  (HSB_O + SLEN*HID)           // feats [S][11]

__device__ __forceinline__ float sigm(float x) { return 1.0f / (1.0f + expf(-x)); }

// -------- sentinel-fill hs (ws is re-poisoned to 0xAA before every launch) ---
__global__ void k_fill(unsigned* __restrict__ p, int n, unsigned val) {
    int i = blockIdx.x * 256 + threadIdx.x;
    int stride = gridDim.x * 256;
    for (; i < n; i += stride) p[i] = val;
}

// -------- tiled transpose Wih [2048][325] -> Wt [325][2048] ------------------
__global__ __launch_bounds__(256) void k_transpose(const float* __restrict__ wf,
        const float* __restrict__ wb, float* __restrict__ ws) {
    __shared__ float tile[32][33];
    const int dir = blockIdx.z;
    const float* src = dir ? wb : wf;                  // [GDIM][XIN]
    float* dst = ws + (dir ? WT_B_O : WT_F_O);         // [XIN][GDIM]
    const int k0 = blockIdx.x * 32, j0 = blockIdx.y * 32;
    const int tx = threadIdx.x, ty = threadIdx.y;
    for (int yy = ty; yy < 32; yy += 8) {
        int k = k0 + tx;
        tile[yy][tx] = (k < XIN) ? src[(size_t)(j0 + yy) * XIN + k] : 0.f;
    }
    __syncthreads();
    for (int yy = ty; yy < 32; yy += 8) {
        int k = k0 + yy;
        if (k < XIN) dst[(size_t)k * GDIM + j0 + tx] = tile[tx][yy];
    }
}

// ---------------- char CNN + global max pool ---------------------------------
__global__ __launch_bounds__(64) void k_charcnn(const int* __restrict__ chars,
        const float* __restrict__ cemb, const float* __restrict__ cw,
        const float* __restrict__ cb, float* __restrict__ ws) {
    int s = blockIdx.x, tid = threadIdx.x;
    __shared__ int ch[LCH];
    __shared__ float ce[LCH][CHE];
    if (tid < LCH) ch[tid] = chars[s * LCH + tid];
    __syncthreads();
    for (int idx = tid; idx < LCH * CHE; idx += 64) {
        int l = idx / CHE, e = idx % CHE;
        ce[l][e] = cemb[ch[l] * CHE + e];
    }
    __syncthreads();
    if (tid < CHO) {
        float best = -1e30f;
        for (int h = 0; h < LCH + 2; ++h) {      // 26 output positions (pad=2)
            float acc = cb[tid];
            #pragma unroll
            for (int kh = 0; kh < 3; ++kh) {
                int l = h - 2 + kh;
                if (l >= 0 && l < LCH) {
                    const float* wp = cw + tid * 75 + kh * CHE;
                    #pragma unroll
                    for (int e = 0; e < CHE; ++e) acc += ce[l][e] * wp[e];
                }
            }
            best = fmaxf(best, acc);
        }
        (ws + CF_O)[s * CHO + tid] = best;
    }
}

// ---------------- input projection: G[s][j] = x[s]·Wih[j] + bih[j]+bhh[j] ----
__global__ __launch_bounds__(256) void k_ingemm(const int* __restrict__ sent,
        const float* __restrict__ wemb,
        const float* __restrict__ bih_f, const float* __restrict__ bhh_f,
        const float* __restrict__ bih_b, const float* __restrict__ bhh_b,
        float* __restrict__ ws) {
    const int rt = blockIdx.x, jt = blockIdx.y, dir = blockIdx.z;
    const float* wt = ws + (dir ? WT_B_O : WT_F_O);
    const float* cf = ws + CF_O;
    float* g = ws + (dir ? GB_O : GF_O);
    const float* bih = dir ? bih_b : bih_f;
    const float* bhh = dir ? bhh_b : bhh_f;
    __shared__ float xt[XIN][32];
    __shared__ int sl[32];
    const int tid = threadIdx.x;
    const int r0 = rt * 32, j0 = jt * 256;
    if (tid < 32) sl[tid] = sent[r0 + tid];
    __syncthreads();
    for (int idx = tid; idx < XIN * 32; idx += 256) {
        int k = idx >> 5, r = idx & 31;
        float v = (k < EMB) ? wemb[(size_t)sl[r] * EMB + k]
                            : cf[(size_t)(r0 + r) * CHO + (k - EMB)];
        xt[k][r] = v;
    }
    __syncthreads();
    const int jg = tid & 31, rg = tid >> 5;
    const int jb = j0 + jg * 8, rb = rg * 4;
    float acc[4][8];
    #pragma unroll
    for (int a = 0; a < 4; ++a)
        #pragma unroll
        for (int b = 0; b < 8; ++b) acc[a][b] = 0.f;
    for (int k = 0; k < XIN; ++k) {
        float4 xv = *(const float4*)&xt[k][rb];
        const float4* wp = (const float4*)(wt + (size_t)k * GDIM + jb);
        float4 w0 = wp[0], w1 = wp[1];
        float xr[4] = {xv.x, xv.y, xv.z, xv.w};
        float wv[8] = {w0.x, w0.y, w0.z, w0.w, w1.x, w1.y, w1.z, w1.w};
        #pragma unroll
        for (int a = 0; a < 4; ++a)
            #pragma unroll
            for (int b = 0; b < 8; ++b) acc[a][b] += xr[a] * wv[b];
    }
    float bs[8];
    #pragma unroll
    for (int b = 0; b < 8; ++b) bs[b] = bih[jb + b] + bhh[jb + b];
    #pragma unroll
    for (int a = 0; a < 4; ++a) {
        float* gp = g + (size_t)(r0 + rb + a) * GDIM + jb;
        #pragma unroll
        for (int b = 0; b < 8; ++b) gp[b] = acc[a][b] + bs[b];
    }
}

// ---------------- fused BiLSTM recurrence ------------------------------------
// 32 WGs, each owns h_f[16w..16w+16) AND h_b[16w..16w+16). Per step every
// thread computes both directions' partial dots (Wf,Wb slices in VGPRs);
// wave0 reduces+publishes forward, wave1 backward (concurrent); then each
// thread polls one u64 of the f-row and one of the b-row in the same spin
// loop — the two publish->observe latencies overlap, paid once per step.
__global__ __launch_bounds__(256, 1) void k_lstm(const float* __restrict__ whh_f,
        const float* __restrict__ whh_b, float* __restrict__ ws) {
    const int w = blockIdx.x;            // 0..NW-1
    const int tid = threadIdx.x;
    const int wave = tid >> 6;           // col slice [128*wave, 128*wave+128)
    const int lane = tid & 63;           // gate row within WG
    const int hbase = w * 16;
    const int q = lane >> 4, hj = lane & 15;
    const int grow = q * HID + hbase + hj;     // global gate row (both dirs)
    const float* gf_p = ws + GF_O;
    const float* gb_p = ws + GB_O;
    float* hsf = ws + HSF_O;
    float* hsb = ws + HSB_O;

    // Whh slices in VGPRs: Wf/Wb[i] = Whh_{f,b}[grow][wave*128 + 4i ..]
    float4 Wf[32], Wb[32];
    {
        const float4* s0 = (const float4*)(whh_f + (size_t)grow * HID + wave * 128);
        const float4* s1 = (const float4*)(whh_b + (size_t)grow * HID + wave * 128);
        #pragma unroll
        for (int i = 0; i < 32; ++i) { Wf[i] = s0[i]; Wb[i] = s1[i]; }
    }

    __shared__ __align__(16) float hf_lds[HID];
    __shared__ __align__(16) float hb_lds[HID];
    __shared__ float pf[256], pb[256];
    for (int i = tid; i < HID; i += 256) { hf_lds[i] = 0.f; hb_lds[i] = 0.f; }
    float c = 0.f;   // c_f in wave0 lanes<16, c_b in wave1 lanes<16
    __syncthreads();

    int sf = 0, sb = SLEN - 1;
    float gin = 0.f;
    if (tid < 64)       gin = gf_p[(size_t)sf * GDIM + grow];
    else if (tid < 128) gin = gb_p[(size_t)sb * GDIM + grow];

    for (int t = 0; t < SLEN; ++t) {
        // ---- both dots: broadcast LDS reads, conflict-free ------------------
        float4 af = {0.f, 0.f, 0.f, 0.f}, ab = {0.f, 0.f, 0.f, 0.f};
        const float4* h4f = (const float4*)(hf_lds + wave * 128);
        const float4* h4b = (const float4*)(hb_lds + wave * 128);
        #pragma unroll
        for (int i = 0; i < 32; ++i) {
            float4 hf = h4f[i], hb = h4b[i];
            af.x += Wf[i].x * hf.x; af.y += Wf[i].y * hf.y;
            af.z += Wf[i].z * hf.z; af.w += Wf[i].w * hf.w;
            ab.x += Wb[i].x * hb.x; ab.y += Wb[i].y * hb.y;
            ab.z += Wb[i].z * hb.z; ab.w += Wb[i].w * hb.w;
        }
        pf[tid] = (af.x + af.y) + (af.z + af.w);
        pb[tid] = (ab.x + ab.y) + (ab.z + ab.w);
        __syncthreads();

        // ---- wave0: forward reduce+publish; wave1: backward (concurrent) ----
        if (tid < 128) {
            const float* part = (tid < 64) ? pf : pb;
            float gsum = part[lane] + part[64 + lane]
                       + part[128 + lane] + part[192 + lane] + gin;
            float gi = __shfl(gsum, hj);
            float gf = __shfl(gsum, 16 + hj);
            float gg = __shfl(gsum, 32 + hj);
            float go = __shfl(gsum, 48 + hj);
            if (lane < 16) {
                c = sigm(gf) * c + sigm(gi) * tanhf(gg);
                float h = sigm(go) * tanhf(c);
                float* row = (tid < 64) ? (hsf + (size_t)sf * HID)
                                        : (hsb + (size_t)sb * HID);
                __hip_atomic_store((unsigned*)&row[hbase + lane],
                                   __float_as_uint(h),
                                   __ATOMIC_RELAXED, __HIP_MEMORY_SCOPE_AGENT);
            }
        }

        // ---- prefetch next step's G rows before the poll spin ---------------
        const int sfn = (t + 1 < SLEN) ? sf + 1 : sf;
        const int sbn = (t + 1 < SLEN) ? sb - 1 : sb;
        if (tid < 64)       gin = gf_p[(size_t)sfn * GDIM + grow];
        else if (tid < 128) gin = gb_p[(size_t)sbn * GDIM + grow];

        // ---- poll both h rows; each thread owns u64 #tid of each ------------
        const unsigned long long* pfp =
            (const unsigned long long*)(hsf + (size_t)sf * HID) + tid;
        const unsigned long long* pbp =
            (const unsigned long long*)(hsb + (size_t)sb * HID) + tid;
        unsigned long long vf = 0, vb = 0;
        bool okf = false, okb = false;
        do {
            if (!okf) {
                vf = __hip_atomic_load(pfp, __ATOMIC_RELAXED,
                                       __HIP_MEMORY_SCOPE_AGENT);
                okf = ((unsigned)vf != SENT) && ((unsigned)(vf >> 32) != SENT);
            }
            if (!okb) {
                vb = __hip_atomic_load(pbp, __ATOMIC_RELAXED,
                                       __HIP_MEMORY_SCOPE_AGENT);
                okb = ((unsigned)vb != SENT) && ((unsigned)(vb >> 32) != SENT);
            }
        } while (!(okf && okb));
        ((unsigned long long*)hf_lds)[tid] = vf;
        ((unsigned long long*)hb_lds)[tid] = vb;
        __syncthreads();
        sf = sfn; sb = sbn;
    }
}

// ---------------- feats = [h_f|h_b] @ h2t_w^T + h2t_b ------------------------
__global__ __launch_bounds__(64) void k_feats(const float* __restrict__ h2tw,
        const float* __restrict__ h2tb, float* __restrict__ ws) {
    const int s = blockIdx.x, l = threadIdx.x;
    const float* hf = ws + HSF_O + (size_t)s * HID;
    const float* hb = ws + HSB_O + (size_t)s * HID;
    float xf[8], xb[8];
    #pragma unroll
    for (int m = 0; m < 8; ++m) { xf[m] = hf[l + 64 * m]; xb[m] = hb[l + 64 * m]; }
    float* feats = ws + FEATS_O;
    for (int t = 0; t < NTAG; ++t) {
        const float* wp = h2tw + (size_t)t * (2 * HID);
        float p = 0.f;
        #pragma unroll
        for (int m = 0; m < 8; ++m)
            p += xf[m] * wp[l + 64 * m] + xb[m] * wp[HID + l + 64 * m];
        #pragma unroll
        for (int o = 32; o; o >>= 1) p += __shfl_down(p, o);
        if (l == 0) feats[(size_t)s * NTAG + t] = p + h2tb[t];
    }
}

// ---------------- Viterbi decode (single wave, bptrs in LDS) -----------------
__global__ __launch_bounds__(64) void k_viterbi(const float* __restrict__ trans,
        float* __restrict__ ws, float* __restrict__ out) {
    const int lane = threadIdx.x;
    __shared__ float fbuf[256 * NTAG];          // feats chunk (11 KB)
    __shared__ unsigned char bp[SLEN * NTAG];   // backpointers (44 KB)
    const float* feats = ws + FEATS_O;
    const int li = (lane < NTAG) ? lane : 0;
    float trow[NTAG];
    #pragma unroll
    for (int jj = 0; jj < NTAG; ++jj)
        trow[jj] = (lane < NTAG) ? trans[lane * NTAG + jj] : NEGV;
    float fv = (lane == TAG_START) ? 0.f : NEGV;
    for (int ch = 0; ch < SLEN / 256; ++ch) {
        for (int idx = lane; idx < 256 * NTAG; idx += 64)
            fbuf[idx] = feats[(size_t)ch * 256 * NTAG + idx];
        __syncthreads();
        for (int ss = 0; ss < 256; ++ss) {
            const int s = ch * 256 + ss;
            float best = -1e30f; int bj = 0;
            #pragma unroll
            for (int jj = 0; jj < NTAG; ++jj) {
                float v = __shfl(fv, jj) + trow[jj];
                if (v > best) { best = v; bj = jj; }   // strict > => first-max
            }
            fv = best + fbuf[ss * NTAG + li];
            if (lane < NTAG) bp[s * NTAG + lane] = (unsigned char)bj;
        }
        __syncthreads();
    }
    float term = fv + ((lane < NTAG) ? trans[TAG_STOP * NTAG + lane] : NEGV);
    if (lane == TAG_START || lane == TAG_STOP) term = NEGV;
    float bestv = -1e30f; int bt = 0;
    #pragma unroll
    for (int jj = 0; jj < NTAG; ++jj) {
        float v = __shfl(term, jj);
        if (v > bestv) { bestv = v; bt = jj; }
    }
    unsigned char* path = (unsigned char*)fbuf;  // reuse
    if (lane == 0) {
        int tag = bt;
        for (int s2 = SLEN - 1; s2 >= 0; --s2) {
            path[s2] = (unsigned char)tag;
            tag = bp[s2 * NTAG + tag];
        }
        out[0] = bestv;
    }
    __syncthreads();
    for (int idx = lane; idx < SLEN; idx += 64)
        out[1 + idx] = (float)path[idx];
}

extern "C" void kernel_launch(void* const* d_in, const int* in_sizes, int n_in,
                              void* d_out, int out_size, void* d_ws, size_t ws_size,
                              hipStream_t stream) {
    const int*   sentence = (const int*)  d_in[0];
    const int*   chars    = (const int*)  d_in[1];
    const float* word_emb = (const float*)d_in[4];
    const float* char_emb = (const float*)d_in[5];
    const float* conv_w   = (const float*)d_in[6];
    const float* conv_b   = (const float*)d_in[7];
    const float* Wih_f    = (const float*)d_in[8];
    const float* Whh_f    = (const float*)d_in[9];
    const float* bih_f    = (const float*)d_in[10];
    const float* bhh_f    = (const float*)d_in[11];
    const float* Wih_b    = (const float*)d_in[12];
    const float* Whh_b    = (const float*)d_in[13];
    const float* bih_b    = (const float*)d_in[14];
    const float* bhh_b    = (const float*)d_in[15];
    const float* h2t_w    = (const float*)d_in[16];
    const float* h2t_b    = (const float*)d_in[17];
    const float* trans    = (const float*)d_in[18];
    float* ws  = (float*)d_ws;
    float* out = (float*)d_out;

    // NaN-sentinel fill of hs (forward+backward are contiguous at HSF_O)
    k_fill<<<2048, 256, 0, stream>>>((unsigned*)(ws + HSF_O), 2 * SLEN * HID, SENT);
    k_transpose<<<dim3((XIN + 31) / 32, GDIM / 32, 2), dim3(32, 8), 0, stream>>>(
        Wih_f, Wih_b, ws);
    k_charcnn<<<SLEN, 64, 0, stream>>>(chars, char_emb, conv_w, conv_b, ws);
    k_ingemm<<<dim3(SLEN / 32, GDIM / 256, 2), 256, 0, stream>>>(
        sentence, word_emb, bih_f, bhh_f, bih_b, bhh_b, ws);
    k_lstm<<<NW, 256, 0, stream>>>(Whh_f, Whh_b, ws);
    k_feats<<<SLEN, 64, 0, stream>>>(h2t_w, h2t_b, ws);
    k_viterbi<<<1, 64, 0, stream>>>(trans, ws, out);
}

// Round 12
// 10750.847 us; speedup vs baseline: 2.0713x; 2.0713x over previous
//
#include <hip/hip_runtime.h>
#include <hip/hip_bf16.h>
#include <math.h>

#define SLEN 4096
#define LCH 24
#define EMB 300
#define CHE 25
#define CHO 25
#define XIN 325      // EMB + CHO
#define HID 512
#define GDIM 2048    // 4*HID
#define NTAG 11
#define TAG_START 9
#define TAG_STOP 10
#define NEGV (-10000.0f)
#define NW 32        // workgroups per LSTM direction
#define SENT 0x7FC00000u   // NaN sentinel: h = sigm*tanh can never be NaN

// ---- ws layout (float units) ----
#define WT_F_O   0u
#define WT_B_O   (WT_F_O + XIN*GDIM)          // Wih^T forward/backward
#define CF_O     (WT_B_O + XIN*GDIM)          // char_feat [S][25]
#define GF_O     (CF_O + SLEN*CHO)            // G forward [S][2048]
#define GB_O     (GF_O + SLEN*GDIM)
#define HSF_O    (GB_O + SLEN*GDIM)           // hs forward [S][512]
#define HSB_O    (HSF_O + SLEN*HID)
#define FEATS_O  (HSB_O + SLEN*HID)           // feats [S][11]

__device__ __forceinline__ float sigm(float x) { return 1.0f / (1.0f + expf(-x)); }

// -------- sentinel-fill hs (ws is re-poisoned to 0xAA before every launch) ---
__global__ void k_fill(unsigned* __restrict__ p, int n, unsigned val) {
    int i = blockIdx.x * 256 + threadIdx.x;
    int stride = gridDim.x * 256;
    for (; i < n; i += stride) p[i] = val;
}

// -------- tiled transpose Wih [2048][325] -> Wt [325][2048] ------------------
__global__ __launch_bounds__(256) void k_transpose(const float* __restrict__ wf,
        const float* __restrict__ wb, float* __restrict__ ws) {
    __shared__ float tile[32][33];
    const int dir = blockIdx.z;
    const float* src = dir ? wb : wf;                  // [GDIM][XIN]
    float* dst = ws + (dir ? WT_B_O : WT_F_O);         // [XIN][GDIM]
    const int k0 = blockIdx.x * 32, j0 = blockIdx.y * 32;
    const int tx = threadIdx.x, ty = threadIdx.y;
    for (int yy = ty; yy < 32; yy += 8) {
        int k = k0 + tx;
        tile[yy][tx] = (k < XIN) ? src[(size_t)(j0 + yy) * XIN + k] : 0.f;
    }
    __syncthreads();
    for (int yy = ty; yy < 32; yy += 8) {
        int k = k0 + yy;
        if (k < XIN) dst[(size_t)k * GDIM + j0 + tx] = tile[tx][yy];
    }
}

// ---------------- char CNN + global max pool ---------------------------------
__global__ __launch_bounds__(64) void k_charcnn(const int* __restrict__ chars,
        const float* __restrict__ cemb, const float* __restrict__ cw,
        const float* __restrict__ cb, float* __restrict__ ws) {
    int s = blockIdx.x, tid = threadIdx.x;
    __shared__ int ch[LCH];
    __shared__ float ce[LCH][CHE];
    if (tid < LCH) ch[tid] = chars[s * LCH + tid];
    __syncthreads();
    for (int idx = tid; idx < LCH * CHE; idx += 64) {
        int l = idx / CHE, e = idx % CHE;
        ce[l][e] = cemb[ch[l] * CHE + e];
    }
    __syncthreads();
    if (tid < CHO) {
        float best = -1e30f;
        for (int h = 0; h < LCH + 2; ++h) {      // 26 output positions (pad=2)
            float acc = cb[tid];
            #pragma unroll
            for (int kh = 0; kh < 3; ++kh) {
                int l = h - 2 + kh;
                if (l >= 0 && l < LCH) {
                    const float* wp = cw + tid * 75 + kh * CHE;
                    #pragma unroll
                    for (int e = 0; e < CHE; ++e) acc += ce[l][e] * wp[e];
                }
            }
            best = fmaxf(best, acc);
        }
        (ws + CF_O)[s * CHO + tid] = best;
    }
}

// ---------------- input projection: G[s][j] = x[s]·Wih[j] + bih[j]+bhh[j] ----
__global__ __launch_bounds__(256) void k_ingemm(const int* __restrict__ sent,
        const float* __restrict__ wemb,
        const float* __restrict__ bih_f, const float* __restrict__ bhh_f,
        const float* __restrict__ bih_b, const float* __restrict__ bhh_b,
        float* __restrict__ ws) {
    const int rt = blockIdx.x, jt = blockIdx.y, dir = blockIdx.z;
    const float* wt = ws + (dir ? WT_B_O : WT_F_O);
    const float* cf = ws + CF_O;
    float* g = ws + (dir ? GB_O : GF_O);
    const float* bih = dir ? bih_b : bih_f;
    const float* bhh = dir ? bhh_b : bhh_f;
    __shared__ float xt[XIN][32];
    __shared__ int sl[32];
    const int tid = threadIdx.x;
    const int r0 = rt * 32, j0 = jt * 256;
    if (tid < 32) sl[tid] = sent[r0 + tid];
    __syncthreads();
    for (int idx = tid; idx < XIN * 32; idx += 256) {
        int k = idx >> 5, r = idx & 31;
        float v = (k < EMB) ? wemb[(size_t)sl[r] * EMB + k]
                            : cf[(size_t)(r0 + r) * CHO + (k - EMB)];
        xt[k][r] = v;
    }
    __syncthreads();
    const int jg = tid & 31, rg = tid >> 5;
    const int jb = j0 + jg * 8, rb = rg * 4;
    float acc[4][8];
    #pragma unroll
    for (int a = 0; a < 4; ++a)
        #pragma unroll
        for (int b = 0; b < 8; ++b) acc[a][b] = 0.f;
    for (int k = 0; k < XIN; ++k) {
        float4 xv = *(const float4*)&xt[k][rb];
        const float4* wp = (const float4*)(wt + (size_t)k * GDIM + jb);
        float4 w0 = wp[0], w1 = wp[1];
        float xr[4] = {xv.x, xv.y, xv.z, xv.w};
        float wv[8] = {w0.x, w0.y, w0.z, w0.w, w1.x, w1.y, w1.z, w1.w};
        #pragma unroll
        for (int a = 0; a < 4; ++a)
            #pragma unroll
            for (int b = 0; b < 8; ++b) acc[a][b] += xr[a] * wv[b];
    }
    float bs[8];
    #pragma unroll
    for (int b = 0; b < 8; ++b) bs[b] = bih[jb + b] + bhh[jb + b];
    #pragma unroll
    for (int a = 0; a < 4; ++a) {
        float* gp = g + (size_t)(r0 + rb + a) * GDIM + jb;
        #pragma unroll
        for (int b = 0; b < 8; ++b) gp[b] = acc[a][b] + bs[b];
    }
}

// ---------------- BiLSTM recurrence (R4 structure + VGPR-pinned W + XCD pack)
// Grid = 256. Under the observed round-robin bid->XCD map (bid%8), fwd's 32
// WGs land on one XCD and bwd's on another, so all sync traffic for a chain
// stays XCD-local. If the map differs, workers scatter: protocol identical
// to the R4-proven agent-scope scheme => still correct, perf ~= R4.
// W slice forced into VGPRs via scalar opaque asm redefinitions (R4 showed
// VGPR_Count=92 < 128: compiler was re-streaming W from L2 every step).
// NOTE: the pin must be on SCALAR operands — "+v" on float4 hits LLVM's
// "tied indirect register inputs" inline-asm limitation (R7 compile fail).
__global__ __launch_bounds__(256, 1) void k_lstm(const float* __restrict__ whh_f,
        const float* __restrict__ whh_b, float* __restrict__ ws) {
    const int xcd = blockIdx.x & 7;
    const int idx = blockIdx.x >> 3;
    if (idx >= NW) return;
    int dir;
    if (xcd == 0) dir = 0;            // forward chain -> XCD 0 (if %8 map)
    else if (xcd == 1) dir = 1;       // backward chain -> XCD 1
    else return;                      // 192 WGs exit immediately
    const int w = idx;
    const int tid = threadIdx.x;
    const int wave = tid >> 6;      // column part: cols [128*wave, 128*(wave+1))
    const int lane = tid & 63;      // gate row within WG
    const int hbase = w * 16;
    const int q = lane >> 4, hj = lane & 15;
    const int grow = q * HID + hbase + hj;     // global gate row
    const float* whh = dir ? whh_b : whh_f;
    const float* gin_p = ws + (dir ? GB_O : GF_O);
    float* hs = ws + (dir ? HSB_O : HSF_O);

    // Whh slice: W[i] = Whh[grow][wave*128 + 4i ..], split into scalar banks
    float W0[32], W1[32], W2[32], W3[32];
    {
        const float4* wsrc = (const float4*)(whh + (size_t)grow * HID + wave * 128);
        #pragma unroll
        for (int i = 0; i < 32; ++i) {
            float4 v = wsrc[i];
            W0[i] = v.x; W1[i] = v.y; W2[i] = v.z; W3[i] = v.w;
        }
    }
    // Pin: opaque scalar redefinitions -> compiler cannot rematerialize from
    // memory, so the 128 weight VGPRs stay register-resident for all steps.
    #pragma unroll
    for (int i = 0; i < 32; ++i)
        asm volatile("" : "+v"(W0[i]), "+v"(W1[i]), "+v"(W2[i]), "+v"(W3[i]));

    __shared__ __align__(16) float h_lds[HID];
    __shared__ float part_lds[256];
    for (int i = tid; i < HID; i += 256) h_lds[i] = 0.f;   // h(-1) = 0
    float c = 0.f;                  // cell state lives in lanes tid<16
    __syncthreads();

    int s = dir ? (SLEN - 1) : 0;
    float gin = 0.f;
    if (tid < 64) gin = gin_p[(size_t)s * GDIM + grow];

    for (int t = 0; t < SLEN; ++t) {
        // ---- dot: partial over this wave's 128-col slice (broadcast reads) --
        float4 a = {0.f, 0.f, 0.f, 0.f};
        const float4* h4 = (const float4*)(h_lds + wave * 128);
        #pragma unroll
        for (int i = 0; i < 32; ++i) {
            float4 h = h4[i];
            a.x += W0[i] * h.x; a.y += W1[i] * h.y;
            a.z += W2[i] * h.z; a.w += W3[i] * h.w;
        }
        part_lds[tid] = (a.x + a.y) + (a.z + a.w);
        __syncthreads();

        if (tid < 64) {
            float gsum = part_lds[lane] + part_lds[64 + lane]
                       + part_lds[128 + lane] + part_lds[192 + lane] + gin;
            float gi = __shfl(gsum, hj);
            float gf = __shfl(gsum, 16 + hj);
            float gg = __shfl(gsum, 32 + hj);
            float go = __shfl(gsum, 48 + hj);
            if (lane < 16) {
                c = sigm(gf) * c + sigm(gi) * tanhf(gg);
                float h = sigm(go) * tanhf(c);
                __hip_atomic_store((unsigned*)&hs[(size_t)s * HID + hbase + lane],
                                   __float_as_uint(h),
                                   __ATOMIC_RELAXED, __HIP_MEMORY_SCOPE_AGENT);
            }
        }

        // ---- prefetch next step's G row before the poll spin ----------------
        const int sn = dir ? (s - 1) : (s + 1);
        const int sc = (t + 1 < SLEN) ? sn : s;
        if (tid < 64) gin = gin_p[(size_t)sc * GDIM + grow];

        // ---- poll h(t) directly (data-as-flag): thread owns words 2tid,2tid+1
        const unsigned long long* srcp =
            (const unsigned long long*)(hs + (size_t)s * HID) + tid;
        unsigned long long v;
        do {
            v = __hip_atomic_load(srcp, __ATOMIC_RELAXED, __HIP_MEMORY_SCOPE_AGENT);
        } while ((unsigned)v == SENT || (unsigned)(v >> 32) == SENT);
        ((unsigned long long*)h_lds)[tid] = v;
        __syncthreads();
        s = sc;
    }
}

// ---------------- feats = [h_f|h_b] @ h2t_w^T + h2t_b ------------------------
__global__ __launch_bounds__(64) void k_feats(const float* __restrict__ h2tw,
        const float* __restrict__ h2tb, float* __restrict__ ws) {
    const int s = blockIdx.x, l = threadIdx.x;
    const float* hf = ws + HSF_O + (size_t)s * HID;
    const float* hb = ws + HSB_O + (size_t)s * HID;
    float xf[8], xb[8];
    #pragma unroll
    for (int m = 0; m < 8; ++m) { xf[m] = hf[l + 64 * m]; xb[m] = hb[l + 64 * m]; }
    float* feats = ws + FEATS_O;
    for (int t = 0; t < NTAG; ++t) {
        const float* wp = h2tw + (size_t)t * (2 * HID);
        float p = 0.f;
        #pragma unroll
        for (int m = 0; m < 8; ++m)
            p += xf[m] * wp[l + 64 * m] + xb[m] * wp[HID + l + 64 * m];
        #pragma unroll
        for (int o = 32; o; o >>= 1) p += __shfl_down(p, o);
        if (l == 0) feats[(size_t)s * NTAG + t] = p + h2tb[t];
    }
}

// ---------------- Viterbi decode (single wave, bptrs in LDS) -----------------
__global__ __launch_bounds__(64) void k_viterbi(const float* __restrict__ trans,
        float* __restrict__ ws, float* __restrict__ out) {
    const int lane = threadIdx.x;
    __shared__ float fbuf[256 * NTAG];          // feats chunk (11 KB)
    __shared__ unsigned char bp[SLEN * NTAG];   // backpointers (44 KB)
    const float* feats = ws + FEATS_O;
    const int li = (lane < NTAG) ? lane : 0;
    float trow[NTAG];
    #pragma unroll
    for (int jj = 0; jj < NTAG; ++jj)
        trow[jj] = (lane < NTAG) ? trans[lane * NTAG + jj] : NEGV;
    float fv = (lane == TAG_START) ? 0.f : NEGV;
    for (int ch = 0; ch < SLEN / 256; ++ch) {
        for (int idx = lane; idx < 256 * NTAG; idx += 64)
            fbuf[idx] = feats[(size_t)ch * 256 * NTAG + idx];
        __syncthreads();
        for (int ss = 0; ss < 256; ++ss) {
            const int s = ch * 256 + ss;
            float best = -1e30f; int bj = 0;
            #pragma unroll
            for (int jj = 0; jj < NTAG; ++jj) {
                float v = __shfl(fv, jj) + trow[jj];
                if (v > best) { best = v; bj = jj; }   // strict > => first-max
            }
            fv = best + fbuf[ss * NTAG + li];
            if (lane < NTAG) bp[s * NTAG + lane] = (unsigned char)bj;
        }
        __syncthreads();
    }
    float term = fv + ((lane < NTAG) ? trans[TAG_STOP * NTAG + lane] : NEGV);
    if (lane == TAG_START || lane == TAG_STOP) term = NEGV;
    float bestv = -1e30f; int bt = 0;
    #pragma unroll
    for (int jj = 0; jj < NTAG; ++jj) {
        float v = __shfl(term, jj);
        if (v > bestv) { bestv = v; bt = jj; }
    }
    unsigned char* path = (unsigned char*)fbuf;  // reuse
    if (lane == 0) {
        int tag = bt;
        for (int s2 = SLEN - 1; s2 >= 0; --s2) {
            path[s2] = (unsigned char)tag;
            tag = bp[s2 * NTAG + tag];
        }
        out[0] = bestv;
    }
    __syncthreads();
    for (int idx = lane; idx < SLEN; idx += 64)
        out[1 + idx] = (float)path[idx];
}

extern "C" void kernel_launch(void* const* d_in, const int* in_sizes, int n_in,
                              void* d_out, int out_size, void* d_ws, size_t ws_size,
                              hipStream_t stream) {
    const int*   sentence = (const int*)  d_in[0];
    const int*   chars    = (const int*)  d_in[1];
    const float* word_emb = (const float*)d_in[4];
    const float* char_emb = (const float*)d_in[5];
    const float* conv_w   = (const float*)d_in[6];
    const float* conv_b   = (const float*)d_in[7];
    const float* Wih_f    = (const float*)d_in[8];
    const float* Whh_f    = (const float*)d_in[9];
    const float* bih_f    = (const float*)d_in[10];
    const float* bhh_f    = (const float*)d_in[11];
    const float* Wih_b    = (const float*)d_in[12];
    const float* Whh_b    = (const float*)d_in[13];
    const float* bih_b    = (const float*)d_in[14];
    const float* bhh_b    = (const float*)d_in[15];
    const float* h2t_w    = (const float*)d_in[16];
    const float* h2t_b    = (const float*)d_in[17];
    const float* trans    = (const float*)d_in[18];
    float* ws  = (float*)d_ws;
    float* out = (float*)d_out;

    // NaN-sentinel fill of hs (forward+backward are contiguous at HSF_O)
    k_fill<<<2048, 256, 0, stream>>>((unsigned*)(ws + HSF_O), 2 * SLEN * HID, SENT);
    k_transpose<<<dim3((XIN + 31) / 32, GDIM / 32, 2), dim3(32, 8), 0, stream>>>(
        Wih_f, Wih_b, ws);
    k_charcnn<<<SLEN, 64, 0, stream>>>(chars, char_emb, conv_w, conv_b, ws);
    k_ingemm<<<dim3(SLEN / 32, GDIM / 256, 2), 256, 0, stream>>>(
        sentence, word_emb, bih_f, bhh_f, bih_b, bhh_b, ws);
    k_lstm<<<NW * 8, 256, 0, stream>>>(Whh_f, Whh_b, ws);
    k_feats<<<SLEN, 64, 0, stream>>>(h2t_w, h2t_b, ws);
    k_viterbi<<<1, 64, 0, stream>>>(trans, ws, out);
}

// Round 13
// 8454.647 us; speedup vs baseline: 2.6339x; 1.2716x over previous
//
#include <hip/hip_runtime.h>
#include <hip/hip_bf16.h>
#include <math.h>

#define SLEN 4096
#define LCH 24
#define EMB 300
#define CHE 25
#define CHO 25
#define XIN 325      // EMB + CHO
#define HID 512
#define GDIM 2048    // 4*HID
#define NTAG 11
#define TAG_START 9
#define TAG_STOP 10
#define NEGV (-10000.0f)
#define NW 32        // workgroups per LSTM direction
#define SENT 0x7FC00000u   // NaN sentinel: h = sigm*tanh can never be NaN

// ---- ws layout (float units) ----
#define WT_F_O   0u
#define WT_B_O   (WT_F_O + XIN*GDIM)          // Wih^T forward/backward
#define CF_O     (WT_B_O + XIN*GDIM)          // char_feat [S][25]
#define GF_O     (CF_O + SLEN*CHO)            // G forward [S][2048]
#define GB_O     (GF_O + SLEN*GDIM)
#define HSF_O    (GB_O + SLEN*GDIM)           // hs forward [S][512]
#define HSB_O    (HSF_O + SLEN*HID)
#define FEATS_O  (HSB_O + SLEN*HID)           // feats [S][11]

__device__ __forceinline__ float sigm(float x) { return 1.0f / (1.0f + expf(-x)); }

// Fast activations for the k_lstm critical path: v_exp/v_rcp based,
// ~1e-6 rel error (argmax-safe: reassociated fp32 sums already inject
// comparable noise vs the JAX reference and tag_seq matched exactly).
__device__ __forceinline__ float frcp(float x) { return __builtin_amdgcn_rcpf(x); }
__device__ __forceinline__ float fsigm(float x) { return frcp(1.0f + __expf(-x)); }
__device__ __forceinline__ float ftanh(float x) {
    float e = __expf(2.0f * x);              // inf-safe: x>>0 -> 1, x<<0 -> -1
    return 1.0f - 2.0f * frcp(e + 1.0f);
}

// -------- sentinel-fill hs (ws is re-poisoned to 0xAA before every launch) ---
__global__ void k_fill(unsigned* __restrict__ p, int n, unsigned val) {
    int i = blockIdx.x * 256 + threadIdx.x;
    int stride = gridDim.x * 256;
    for (; i < n; i += stride) p[i] = val;
}

// -------- tiled transpose Wih [2048][325] -> Wt [325][2048] ------------------
__global__ __launch_bounds__(256) void k_transpose(const float* __restrict__ wf,
        const float* __restrict__ wb, float* __restrict__ ws) {
    __shared__ float tile[32][33];
    const int dir = blockIdx.z;
    const float* src = dir ? wb : wf;                  // [GDIM][XIN]
    float* dst = ws + (dir ? WT_B_O : WT_F_O);         // [XIN][GDIM]
    const int k0 = blockIdx.x * 32, j0 = blockIdx.y * 32;
    const int tx = threadIdx.x, ty = threadIdx.y;
    for (int yy = ty; yy < 32; yy += 8) {
        int k = k0 + tx;
        tile[yy][tx] = (k < XIN) ? src[(size_t)(j0 + yy) * XIN + k] : 0.f;
    }
    __syncthreads();
    for (int yy = ty; yy < 32; yy += 8) {
        int k = k0 + yy;
        if (k < XIN) dst[(size_t)k * GDIM + j0 + tx] = tile[tx][yy];
    }
}

// ---------------- char CNN + global max pool ---------------------------------
__global__ __launch_bounds__(64) void k_charcnn(const int* __restrict__ chars,
        const float* __restrict__ cemb, const float* __restrict__ cw,
        const float* __restrict__ cb, float* __restrict__ ws) {
    int s = blockIdx.x, tid = threadIdx.x;
    __shared__ int ch[LCH];
    __shared__ float ce[LCH][CHE];
    if (tid < LCH) ch[tid] = chars[s * LCH + tid];
    __syncthreads();
    for (int idx = tid; idx < LCH * CHE; idx += 64) {
        int l = idx / CHE, e = idx % CHE;
        ce[l][e] = cemb[ch[l] * CHE + e];
    }
    __syncthreads();
    if (tid < CHO) {
        float best = -1e30f;
        for (int h = 0; h < LCH + 2; ++h) {      // 26 output positions (pad=2)
            float acc = cb[tid];
            #pragma unroll
            for (int kh = 0; kh < 3; ++kh) {
                int l = h - 2 + kh;
                if (l >= 0 && l < LCH) {
                    const float* wp = cw + tid * 75 + kh * CHE;
                    #pragma unroll
                    for (int e = 0; e < CHE; ++e) acc += ce[l][e] * wp[e];
                }
            }
            best = fmaxf(best, acc);
        }
        (ws + CF_O)[s * CHO + tid] = best;
    }
}

// ---------------- input projection: G[s][j] = x[s]·Wih[j] + bih[j]+bhh[j] ----
__global__ __launch_bounds__(256) void k_ingemm(const int* __restrict__ sent,
        const float* __restrict__ wemb,
        const float* __restrict__ bih_f, const float* __restrict__ bhh_f,
        const float* __restrict__ bih_b, const float* __restrict__ bhh_b,
        float* __restrict__ ws) {
    const int rt = blockIdx.x, jt = blockIdx.y, dir = blockIdx.z;
    const float* wt = ws + (dir ? WT_B_O : WT_F_O);
    const float* cf = ws + CF_O;
    float* g = ws + (dir ? GB_O : GF_O);
    const float* bih = dir ? bih_b : bih_f;
    const float* bhh = dir ? bhh_b : bhh_f;
    __shared__ float xt[XIN][32];
    __shared__ int sl[32];
    const int tid = threadIdx.x;
    const int r0 = rt * 32, j0 = jt * 256;
    if (tid < 32) sl[tid] = sent[r0 + tid];
    __syncthreads();
    for (int idx = tid; idx < XIN * 32; idx += 256) {
        int k = idx >> 5, r = idx & 31;
        float v = (k < EMB) ? wemb[(size_t)sl[r] * EMB + k]
                            : cf[(size_t)(r0 + r) * CHO + (k - EMB)];
        xt[k][r] = v;
    }
    __syncthreads();
    const int jg = tid & 31, rg = tid >> 5;
    const int jb = j0 + jg * 8, rb = rg * 4;
    float acc[4][8];
    #pragma unroll
    for (int a = 0; a < 4; ++a)
        #pragma unroll
        for (int b = 0; b < 8; ++b) acc[a][b] = 0.f;
    for (int k = 0; k < XIN; ++k) {
        float4 xv = *(const float4*)&xt[k][rb];
        const float4* wp = (const float4*)(wt + (size_t)k * GDIM + jb);
        float4 w0 = wp[0], w1 = wp[1];
        float xr[4] = {xv.x, xv.y, xv.z, xv.w};
        float wv[8] = {w0.x, w0.y, w0.z, w0.w, w1.x, w1.y, w1.z, w1.w};
        #pragma unroll
        for (int a = 0; a < 4; ++a)
            #pragma unroll
            for (int b = 0; b < 8; ++b) acc[a][b] += xr[a] * wv[b];
    }
    float bs[8];
    #pragma unroll
    for (int b = 0; b < 8; ++b) bs[b] = bih[jb + b] + bhh[jb + b];
    #pragma unroll
    for (int a = 0; a < 4; ++a) {
        float* gp = g + (size_t)(r0 + rb + a) * GDIM + jb;
        #pragma unroll
        for (int b = 0; b < 8; ++b) gp[b] = acc[a][b] + bs[b];
    }
}

// ---------------- BiLSTM recurrence — single-barrier step --------------------
// R12 post-mortem: weight path is NOT critical (FETCH 3.3x change, time flat);
// agent atomics are serviced at a common coherence point (XCD pack time-flat).
// => attack the serialized intra-WG chain around the RT instead:
//  * ONE barrier/step: part_lds double-buffered (removes the WAR barrier).
//    h_lds has NO cross-wave dependency: wave v polls u64 words [64v,64v+64)
//    = floats [128v,128v+128) = exactly the slice its own dot reads.
//  * fast activations (v_exp/v_rcp) on the publish critical path.
//  * XCD pack kept (FETCH 228->69MB, free); VGPR pin dropped (spilled anyway,
//    cost 3%).
__global__ __launch_bounds__(256, 1) void k_lstm(const float* __restrict__ whh_f,
        const float* __restrict__ whh_b, float* __restrict__ ws) {
    const int xcd = blockIdx.x & 7;
    const int idx = blockIdx.x >> 3;
    if (idx >= NW) return;
    int dir;
    if (xcd == 0) dir = 0;            // forward chain -> XCD 0 (if %8 map)
    else if (xcd == 1) dir = 1;       // backward chain -> XCD 1
    else return;                      // 192 WGs exit immediately
    const int w = idx;
    const int tid = threadIdx.x;
    const int wave = tid >> 6;      // column part: cols [128*wave, 128*(wave+1))
    const int lane = tid & 63;      // gate row within WG
    const int hbase = w * 16;
    const int q = lane >> 4, hj = lane & 15;
    const int grow = q * HID + hbase + hj;     // global gate row
    const float* whh = dir ? whh_b : whh_f;
    const float* gin_p = ws + (dir ? GB_O : GF_O);
    float* hs = ws + (dir ? HSB_O : HSF_O);

    // Whh slice (compiler-managed residency; R4-proven)
    float4 W[32];
    const float4* wsrc = (const float4*)(whh + (size_t)grow * HID + wave * 128);
    #pragma unroll
    for (int i = 0; i < 32; ++i) W[i] = wsrc[i];

    __shared__ __align__(16) float h_lds[HID];
    __shared__ float part_lds[2][256];    // double-buffered: kills barrier2
    for (int i = tid; i < HID; i += 256) h_lds[i] = 0.f;   // h(-1) = 0
    float c = 0.f;                  // cell state lives in lanes tid<16
    __syncthreads();

    int s = dir ? (SLEN - 1) : 0;
    float gin = 0.f;
    if (tid < 64) gin = gin_p[(size_t)s * GDIM + grow];

    for (int t = 0; t < SLEN; ++t) {
        const int buf = t & 1;
        // ---- dot over own wave's 128-col slice (broadcast LDS reads) --------
        float4 a = {0.f, 0.f, 0.f, 0.f};
        const float4* h4 = (const float4*)(h_lds + wave * 128);
        #pragma unroll
        for (int i = 0; i < 32; ++i) {
            float4 h = h4[i];
            a.x += W[i].x * h.x; a.y += W[i].y * h.y;
            a.z += W[i].z * h.z; a.w += W[i].w * h.w;
        }
        part_lds[buf][tid] = (a.x + a.y) + (a.z + a.w);
        __syncthreads();               // the ONLY barrier per step

        // ---- wave0: reduce + fast activations + publish ---------------------
        if (tid < 64) {
            float gsum = part_lds[buf][lane] + part_lds[buf][64 + lane]
                       + part_lds[buf][128 + lane] + part_lds[buf][192 + lane]
                       + gin;
            float gi = __shfl(gsum, hj);
            float gf = __shfl(gsum, 16 + hj);
            float gg = __shfl(gsum, 32 + hj);
            float go = __shfl(gsum, 48 + hj);
            if (lane < 16) {
                c = fsigm(gf) * c + fsigm(gi) * ftanh(gg);
                float h = fsigm(go) * ftanh(c);
                __hip_atomic_store((unsigned*)&hs[(size_t)s * HID + hbase + lane],
                                   __float_as_uint(h),
                                   __ATOMIC_RELAXED, __HIP_MEMORY_SCOPE_AGENT);
            }
        }

        // ---- prefetch next step's G row (overlaps the poll) -----------------
        const int sn = dir ? (s - 1) : (s + 1);
        const int sc = (t + 1 < SLEN) ? sn : s;
        if (tid < 64) gin = gin_p[(size_t)sc * GDIM + grow];

        // ---- poll own u64 of h(t); wave-local slice -> no barrier needed ----
        const unsigned long long* srcp =
            (const unsigned long long*)(hs + (size_t)s * HID) + tid;
        unsigned long long v;
        do {
            v = __hip_atomic_load(srcp, __ATOMIC_RELAXED, __HIP_MEMORY_SCOPE_AGENT);
        } while ((unsigned)v == SENT || (unsigned)(v >> 32) == SENT);
        ((unsigned long long*)h_lds)[tid] = v;   // intra-wave RAW: lgkmcnt only
        s = sc;
    }
}

// ---------------- feats = [h_f|h_b] @ h2t_w^T + h2t_b ------------------------
__global__ __launch_bounds__(64) void k_feats(const float* __restrict__ h2tw,
        const float* __restrict__ h2tb, float* __restrict__ ws) {
    const int s = blockIdx.x, l = threadIdx.x;
    const float* hf = ws + HSF_O + (size_t)s * HID;
    const float* hb = ws + HSB_O + (size_t)s * HID;
    float xf[8], xb[8];
    #pragma unroll
    for (int m = 0; m < 8; ++m) { xf[m] = hf[l + 64 * m]; xb[m] = hb[l + 64 * m]; }
    float* feats = ws + FEATS_O;
    for (int t = 0; t < NTAG; ++t) {
        const float* wp = h2tw + (size_t)t * (2 * HID);
        float p = 0.f;
        #pragma unroll
        for (int m = 0; m < 8; ++m)
            p += xf[m] * wp[l + 64 * m] + xb[m] * wp[HID + l + 64 * m];
        #pragma unroll
        for (int o = 32; o; o >>= 1) p += __shfl_down(p, o);
        if (l == 0) feats[(size_t)s * NTAG + t] = p + h2tb[t];
    }
}

// ---------------- Viterbi decode (single wave, bptrs in LDS) -----------------
__global__ __launch_bounds__(64) void k_viterbi(const float* __restrict__ trans,
        float* __restrict__ ws, float* __restrict__ out) {
    const int lane = threadIdx.x;
    __shared__ float fbuf[256 * NTAG];          // feats chunk (11 KB)
    __shared__ unsigned char bp[SLEN * NTAG];   // backpointers (44 KB)
    const float* feats = ws + FEATS_O;
    const int li = (lane < NTAG) ? lane : 0;
    float trow[NTAG];
    #pragma unroll
    for (int jj = 0; jj < NTAG; ++jj)
        trow[jj] = (lane < NTAG) ? trans[lane * NTAG + jj] : NEGV;
    float fv = (lane == TAG_START) ? 0.f : NEGV;
    for (int ch = 0; ch < SLEN / 256; ++ch) {
        for (int idx = lane; idx < 256 * NTAG; idx += 64)
            fbuf[idx] = feats[(size_t)ch * 256 * NTAG + idx];
        __syncthreads();
        for (int ss = 0; ss < 256; ++ss) {
            const int s = ch * 256 + ss;
            float best = -1e30f; int bj = 0;
            #pragma unroll
            for (int jj = 0; jj < NTAG; ++jj) {
                float v = __shfl(fv, jj) + trow[jj];
                if (v > best) { best = v; bj = jj; }   // strict > => first-max
            }
            fv = best + fbuf[ss * NTAG + li];
            if (lane < NTAG) bp[s * NTAG + lane] = (unsigned char)bj;
        }
        __syncthreads();
    }
    float term = fv + ((lane < NTAG) ? trans[TAG_STOP * NTAG + lane] : NEGV);
    if (lane == TAG_START || lane == TAG_STOP) term = NEGV;
    float bestv = -1e30f; int bt = 0;
    #pragma unroll
    for (int jj = 0; jj < NTAG; ++jj) {
        float v = __shfl(term, jj);
        if (v > bestv) { bestv = v; bt = jj; }
    }
    unsigned char* path = (unsigned char*)fbuf;  // reuse
    if (lane == 0) {
        int tag = bt;
        for (int s2 = SLEN - 1; s2 >= 0; --s2) {
            path[s2] = (unsigned char)tag;
            tag = bp[s2 * NTAG + tag];
        }
        out[0] = bestv;
    }
    __syncthreads();
    for (int idx = lane; idx < SLEN; idx += 64)
        out[1 + idx] = (float)path[idx];
}

extern "C" void kernel_launch(void* const* d_in, const int* in_sizes, int n_in,
                              void* d_out, int out_size, void* d_ws, size_t ws_size,
                              hipStream_t stream) {
    const int*   sentence = (const int*)  d_in[0];
    const int*   chars    = (const int*)  d_in[1];
    const float* word_emb = (const float*)d_in[4];
    const float* char_emb = (const float*)d_in[5];
    const float* conv_w   = (const float*)d_in[6];
    const float* conv_b   = (const float*)d_in[7];
    const float* Wih_f    = (const float*)d_in[8];
    const float* Whh_f    = (const float*)d_in[9];
    const float* bih_f    = (const float*)d_in[10];
    const float* bhh_f    = (const float*)d_in[11];
    const float* Wih_b    = (const float*)d_in[12];
    const float* Whh_b    = (const float*)d_in[13];
    const float* bih_b    = (const float*)d_in[14];
    const float* bhh_b    = (const float*)d_in[15];
    const float* h2t_w    = (const float*)d_in[16];
    const float* h2t_b    = (const float*)d_in[17];
    const float* trans    = (const float*)d_in[18];
    float* ws  = (float*)d_ws;
    float* out = (float*)d_out;

    // NaN-sentinel fill of hs (forward+backward are contiguous at HSF_O)
    k_fill<<<2048, 256, 0, stream>>>((unsigned*)(ws + HSF_O), 2 * SLEN * HID, SENT);
    k_transpose<<<dim3((XIN + 31) / 32, GDIM / 32, 2), dim3(32, 8), 0, stream>>>(
        Wih_f, Wih_b, ws);
    k_charcnn<<<SLEN, 64, 0, stream>>>(chars, char_emb, conv_w, conv_b, ws);
    k_ingemm<<<dim3(SLEN / 32, GDIM / 256, 2), 256, 0, stream>>>(
        sentence, word_emb, bih_f, bhh_f, bih_b, bhh_b, ws);
    k_lstm<<<NW * 8, 256, 0, stream>>>(Whh_f, Whh_b, ws);
    k_feats<<<SLEN, 64, 0, stream>>>(h2t_w, h2t_b, ws);
    k_viterbi<<<1, 64, 0, stream>>>(trans, ws, out);
}